// Round 26
// baseline (41.790 us; speedup 1.0000x reference)
//
#include <hip/hip_runtime.h>
#include <math.h>

namespace {

constexpr int Bn = 2, Hn = 128, Wn = 128, Cn = 256, Vn = 64;

typedef float f32x2 __attribute__((ext_vector_type(2)));

// Packed fp32 FMA: d = a*b + c on both halves of a 64-bit VGPR pair.
// MI355X fp32 peak (157.3 TF) = 2 FLOP/lane/cy = v_pk_fma_f32; scalar
// v_fma_f32 is half rate. The compiler can't form these from our serial
// accumulation chains (fp reassociation), so force via inline asm.
__device__ __forceinline__ f32x2 pk_fma(f32x2 a, f32x2 b, f32x2 c) {
    f32x2 d;
    asm("v_pk_fma_f32 %0, %1, %2, %3" : "=v"(d) : "v"(a), "v"(b), "v"(c));
    return d;
}

__device__ __forceinline__ void load8v(f32x2* r, const float* p) {
    float4 a = *(const float4*)(p);
    float4 b = *(const float4*)(p + 4);
    r[0] = f32x2{a.x, a.y}; r[1] = f32x2{a.z, a.w};
    r[2] = f32x2{b.x, b.y}; r[3] = f32x2{b.z, b.w};
}

// DPP-based add of a row-permuted copy (VALU pipe). CTRL compile-time.
// 0xB1=xor1, 0x4E=xor2, 0x124=row_ror:4, 0x128=row_ror:8.
template <int CTRL>
__device__ __forceinline__ float row_add(float v) {
    int sh = __builtin_amdgcn_update_dpp(0, __float_as_int(v), CTRL, 0xF, 0xF, true);
    return v + __int_as_float(sh);
}

// Sum over the 32 split lanes: 4 DPP adds + ONE ds_swizzle xor16 (R12-proven).
__device__ __forceinline__ float split_reduce(float v) {
    v = row_add<0xB1>(v);
    v = row_add<0x4E>(v);
    v = row_add<0x124>(v);
    v = row_add<0x128>(v);
    v += __int_as_float(__builtin_amdgcn_ds_swizzle(__float_as_int(v), 0x401F)); // xor16
    return v;
}

// R25 base (35.0us best: 8 pairs x 32 splits, DPP reduce, fixed-shift
// softmax C=self, hoisted value loads) with ONE change: all dot-product and
// value FMAs converted to v_pk_fma_f32 (even/odd partial sums in a 64-bit
// pair, horizontal add at the end). Halves FMA issue count: score 80->40+10,
// value 20->10 per di-lane. Also drops the overflow clamp (dead on this
// data: sc-self <= -100 typically; exp underflows to 0 harmlessly).
// Numerics: partial-sum order changes -> absmax ~1e-5 (threshold 0.101).
__global__ __launch_bounds__(256)
void local_attn_kernel(const float* __restrict__ mainp,
                       const float* __restrict__ mainv,
                       const float* __restrict__ refp,
                       const float* __restrict__ refv,
                       float* __restrict__ outp)
{
    const int t = threadIdx.x;
    const int s = t & 31;       // channel split 0..31 (8 ch each)
    const int g = t >> 5;       // pixel-pair 0..7
    const int blk = blockIdx.x; // 0 .. 2047
    const int seg = blk & 7;
    const int h   = (blk >> 3) & (Hn - 1);
    const int b   = blk >> 10;
    const int w0  = seg * 16 + g * 2;   // px0 = w0, px1 = w0+1
    const int rowbase = b * Hn + h;

    // main channels as packed pairs: 4 x f32x2 per pixel
    f32x2 m0[4], m1[4];
    const float* mp = mainp + ((size_t)rowbase * Wn + w0) * Cn + s * 8;
    load8v(m0, mp);
    load8v(m1, mp + Cn);

    // self scores (slot 25): the softmax shift C
    float self0, self1;
    {
        f32x2 a2 = f32x2{0.f, 0.f}, b2 = f32x2{0.f, 0.f};
        #pragma unroll
        for (int c = 0; c < 4; ++c) {
            a2 = pk_fma(m0[c], m0[c], a2);
            b2 = pk_fma(m1[c], m1[c], b2);
        }
        self0 = split_reduce(a2[0] + a2[1]);
        self1 = split_reduce(b2[0] + b2[1]);
    }

    // accumulators seeded with the self slot (weight exp(0)=1)
    float den0 = 1.f, den1 = 1.f;
    f32x2 acc0, acc1;
    {
        const float* mvp = mainv + ((size_t)rowbase * Wn + w0) * Vn + s * 2;
        acc0 = *(const f32x2*)(mvp);
        acc1 = *(const f32x2*)(mvp + Vn);
    }

    #pragma unroll 1
    for (int di = 0; di < 5; ++di) {
        const int hh = h + di - 2;
        const bool rowok = (unsigned)hh < (unsigned)Hn;
        const size_t rbase = (size_t)(b * Hn + (rowok ? hh : 0)) * Wn;
        const float* rp = refp + rbase * Cn + s * 8;

        // ---- scores: 6 shared column loads, packed dot products ----
        float sc0[5], sc1[5];
        #pragma unroll
        for (int o = 0; o < 6; ++o) {
            const int col = w0 - 2 + o;
            const bool ok = rowok && (unsigned)col < (unsigned)Wn;
            f32x2 r[4];
            #pragma unroll
            for (int c = 0; c < 4; ++c) r[c] = f32x2{0.f, 0.f};
            if (ok) load8v(r, rp + (size_t)col * Cn);
            if (o < 5) {
                f32x2 a2 = f32x2{0.f, 0.f};
                #pragma unroll
                for (int c = 0; c < 4; ++c) a2 = pk_fma(m0[c], r[c], a2);
                sc0[o] = a2[0] + a2[1];
            }
            if (o >= 1) {
                f32x2 a2 = f32x2{0.f, 0.f};
                #pragma unroll
                for (int c = 0; c < 4; ++c) a2 = pk_fma(m1[c], r[c], a2);
                sc1[o - 1] = a2[0] + a2[1];
            }
        }

        // ---- hoisted value loads: latency overlaps reduce + exp ----
        const float* rvp = refv + rbase * Vn + s * 2;
        f32x2 rv[6];
        #pragma unroll
        for (int o = 0; o < 6; ++o) {
            const int col = w0 - 2 + o;
            rv[o] = f32x2{0.f, 0.f};
            if (rowok && (unsigned)col < (unsigned)Wn)
                rv[o] = *(const f32x2*)(rvp + (size_t)col * Vn);
        }

        // reduce partial dots across the 32 split lanes
        #pragma unroll
        for (int k = 0; k < 5; ++k) {
            sc0[k] = split_reduce(sc0[k]);
            sc1[k] = split_reduce(sc1[k]);
        }

        // ---- fixed-shift weights: wk = exp(sc - self) ----
        #pragma unroll
        for (int k = 0; k < 5; ++k) {
            sc0[k] = __expf(sc0[k] - self0);
            sc1[k] = __expf(sc1[k] - self1);
            den0 += sc0[k];
            den1 += sc1[k];
        }

        // ---- values: packed FMAs from prefetched rv ----
        #pragma unroll
        for (int o = 0; o < 6; ++o) {
            if (o < 5) {
                const f32x2 wk2 = f32x2{sc0[o], sc0[o]};
                acc0 = pk_fma(wk2, rv[o], acc0);
            }
            if (o >= 1) {
                const f32x2 wk2 = f32x2{sc1[o - 1], sc1[o - 1]};
                acc1 = pk_fma(wk2, rv[o], acc1);
            }
        }
    }

    const float inv0 = 1.f / den0, inv1 = 1.f / den1;
    float* op = outp + ((size_t)rowbase * Wn + w0) * Vn + s * 2;
    f32x2 o0, o1;
    o0[0] = acc0[0] * inv0; o0[1] = acc0[1] * inv0;
    o1[0] = acc1[0] * inv1; o1[1] = acc1[1] * inv1;
    *(f32x2*)(op)      = o0;
    *(f32x2*)(op + Vn) = o1;
}

} // namespace

extern "C" void kernel_launch(void* const* d_in, const int* in_sizes, int n_in,
                              void* d_out, int out_size, void* d_ws, size_t ws_size,
                              hipStream_t stream)
{
    const float* mainp = (const float*)d_in[0];
    const float* mainv = (const float*)d_in[1];
    const float* refp  = (const float*)d_in[2];
    const float* refv  = (const float*)d_in[3];
    float* outp = (float*)d_out;

    dim3 grid(Bn * Hn * 8);   // 2048 blocks: one per 16-pixel row segment
    dim3 block(256);          // 8 pairs x 32 splits
    hipLaunchKernelGGL(local_attn_kernel, grid, block, 0, stream,
                       mainp, mainv, refp, refv, outp);
}

// Round 27
// 34.947 us; speedup vs baseline: 1.1958x; 1.1958x over previous
//
#include <hip/hip_runtime.h>
#include <math.h>

namespace {

constexpr int Bn = 2, Hn = 128, Wn = 128, Cn = 256, Vn = 64;

__device__ __forceinline__ void load8(float* r, const float* p) {
    float4 a = *(const float4*)(p);
    float4 b = *(const float4*)(p + 4);
    r[0]=a.x; r[1]=a.y; r[2]=a.z; r[3]=a.w;
    r[4]=b.x; r[5]=b.y; r[6]=b.z; r[7]=b.w;
}

// DPP-based add of a row-permuted copy (VALU pipe, not DS). CTRL is a
// compile-time template arg. 0xB1=xor1, 0x4E=xor2, 0x124=row_ror:4,
// 0x128=row_ror:8.
template <int CTRL>
__device__ __forceinline__ float row_add(float v) {
    int sh = __builtin_amdgcn_update_dpp(0, __float_as_int(v), CTRL, 0xF, 0xF, true);
    return v + __int_as_float(sh);
}

// Sum over the 32 split lanes (lane bits 0..4): 4 DPP adds + ONE ds_swizzle
// xor16 (R12-proven; replaced 5 DS-pipe shuffles, +10%).
__device__ __forceinline__ float split_reduce(float v) {
    v = row_add<0xB1>(v);
    v = row_add<0x4E>(v);
    v = row_add<0x124>(v);
    v = row_add<0x128>(v);
    v += __int_as_float(__builtin_amdgcn_ds_swizzle(__float_as_int(v), 0x401F)); // xor16
    return v;
}

// FINAL (best measured: 35.02us, R25). Structure: 256 thr = 8 pixel-pairs x
// 32 channel-splits; lane owns 2 adjacent px x 8 ch. Rolled di loop; scores
// via per-lane partial dots + DPP/swizzle cross-lane reduce; FIXED-SHIFT
// softmax (C = self; shift cancels in the num/den ratio, removing the
// online-rescale serial chain); value loads hoisted above the reduce so
// their latency overlaps the reduce+exp VALU work; exec-mask predication
// for OOB (zero-pad semantics: OOB score slots contribute exp(0-C) to den
// and 0 value, exactly matching the reference's zero-padded patches).
// Grid 2048 = 8 segments/row keeps the default XCD round-robin h-local
// (R5 showed breaking this triples FETCH).
//
// Session evidence for why this is the plateau: 16 levers tried (masking
// styles, px-blocking 1/2/4, block 128/256/512, splits 8/16/32, XCD
// swizzles, LDS staging x3, di-parallel two-pass, MFMA x3, unroll-2, phase
// stagger, pk_fma) - only DPP reduce (+10%) and fixed-shift (+1%) won.
// VALU ~42% + L1 ~45%, serialized; residency pinned ~2.6 waves/SIMD.
__global__ __launch_bounds__(256)
void local_attn_kernel(const float* __restrict__ mainp,
                       const float* __restrict__ mainv,
                       const float* __restrict__ refp,
                       const float* __restrict__ refv,
                       float* __restrict__ outp)
{
    const int t = threadIdx.x;
    const int s = t & 31;       // channel split 0..31 (8 ch each)
    const int g = t >> 5;       // pixel-pair 0..7
    const int blk = blockIdx.x; // 0 .. 2047
    const int seg = blk & 7;
    const int h   = (blk >> 3) & (Hn - 1);
    const int b   = blk >> 10;
    const int w0  = seg * 16 + g * 2;   // px0 = w0, px1 = w0+1
    const int rowbase = b * Hn + h;

    // main channels: 8 each for px0/px1 (ch = s*8 .. s*8+7)
    float m0[8], m1[8];
    const float* mp = mainp + ((size_t)rowbase * Wn + w0) * Cn + s * 8;
    load8(m0, mp);
    load8(m1, mp + Cn);

    // self scores (slot 25): the softmax shift C
    float self0 = 0.f, self1 = 0.f;
    #pragma unroll
    for (int c = 0; c < 8; ++c) {
        self0 = fmaf(m0[c], m0[c], self0);
        self1 = fmaf(m1[c], m1[c], self1);
    }
    self0 = split_reduce(self0);
    self1 = split_reduce(self1);

    // accumulators seeded with the self slot: weight exp(self-C) = 1 exactly
    float den0 = 1.f, den1 = 1.f;
    float acc0[2], acc1[2];
    {
        const float* mvp = mainv + ((size_t)rowbase * Wn + w0) * Vn + s * 2;
        float2 a = *(const float2*)(mvp);
        float2 c = *(const float2*)(mvp + Vn);
        acc0[0] = a.x; acc0[1] = a.y;
        acc1[0] = c.x; acc1[1] = c.y;
    }

    #pragma unroll 1
    for (int di = 0; di < 5; ++di) {
        const int hh = h + di - 2;
        const bool rowok = (unsigned)hh < (unsigned)Hn;
        const size_t rbase = (size_t)(b * Hn + (rowok ? hh : 0)) * Wn;
        const float* rp = refp + rbase * Cn + s * 8;

        // ---- scores: 6 shared column loads serve both pixels ----
        float sc0[5], sc1[5];
        #pragma unroll
        for (int o = 0; o < 6; ++o) {
            const int col = w0 - 2 + o;
            const bool ok = rowok && (unsigned)col < (unsigned)Wn;
            float r[8];
            #pragma unroll
            for (int c = 0; c < 8; ++c) r[c] = 0.f;
            if (ok) load8(r, rp + (size_t)col * Cn);
            if (o < 5) {
                float a = 0.f;
                #pragma unroll
                for (int c = 0; c < 8; ++c) a = fmaf(m0[c], r[c], a);
                sc0[o] = a;
            }
            if (o >= 1) {
                float a = 0.f;
                #pragma unroll
                for (int c = 0; c < 8; ++c) a = fmaf(m1[c], r[c], a);
                sc1[o - 1] = a;
            }
        }

        // ---- hoisted value loads: latency overlaps reduce + exp ----
        const float* rvp = refv + rbase * Vn + s * 2;
        float2 rv[6];
        #pragma unroll
        for (int o = 0; o < 6; ++o) {
            const int col = w0 - 2 + o;
            rv[o] = make_float2(0.f, 0.f);
            if (rowok && (unsigned)col < (unsigned)Wn)
                rv[o] = *(const float2*)(rvp + (size_t)col * Vn);
        }

        // reduce partial dots across the 32 split lanes
        #pragma unroll
        for (int k = 0; k < 5; ++k) {
            sc0[k] = split_reduce(sc0[k]);
            sc1[k] = split_reduce(sc1[k]);
        }

        // ---- fixed-shift weights: wk = exp(sc - self), clamped for safety
        #pragma unroll
        for (int k = 0; k < 5; ++k) {
            sc0[k] = __expf(fminf(sc0[k] - self0, 60.f));
            sc1[k] = __expf(fminf(sc1[k] - self1, 60.f));
            den0 += sc0[k];
            den1 += sc1[k];
        }

        // ---- values: FMAs from prefetched rv ----
        #pragma unroll
        for (int o = 0; o < 6; ++o) {
            if (o < 5) {
                const float wkj = sc0[o];
                acc0[0] = fmaf(wkj, rv[o].x, acc0[0]);
                acc0[1] = fmaf(wkj, rv[o].y, acc0[1]);
            }
            if (o >= 1) {
                const float wkj = sc1[o - 1];
                acc1[0] = fmaf(wkj, rv[o].x, acc1[0]);
                acc1[1] = fmaf(wkj, rv[o].y, acc1[1]);
            }
        }
    }

    const float inv0 = 1.f / den0, inv1 = 1.f / den1;
    float* op = outp + ((size_t)rowbase * Wn + w0) * Vn + s * 2;
    float2 o0, o1;
    o0.x = acc0[0] * inv0; o0.y = acc0[1] * inv0;
    o1.x = acc1[0] * inv1; o1.y = acc1[1] * inv1;
    *(float2*)(op)      = o0;
    *(float2*)(op + Vn) = o1;
}

} // namespace

extern "C" void kernel_launch(void* const* d_in, const int* in_sizes, int n_in,
                              void* d_out, int out_size, void* d_ws, size_t ws_size,
                              hipStream_t stream)
{
    const float* mainp = (const float*)d_in[0];
    const float* mainv = (const float*)d_in[1];
    const float* refp  = (const float*)d_in[2];
    const float* refv  = (const float*)d_in[3];
    float* outp = (float*)d_out;

    dim3 grid(Bn * Hn * 8);   // 2048 blocks: one per 16-pixel row segment
    dim3 block(256);          // 8 pairs x 32 splits
    hipLaunchKernelGGL(local_attn_kernel, grid, block, 0, stream,
                       mainp, mainv, refp, refv, outp);
}